// Round 3
// baseline (908.091 us; speedup 1.0000x reference)
//
#include <hip/hip_runtime.h>

// GCN: 100K nodes, 3.2M edges, 128 -> 16 -> 16 -> 16 -> 2, mean-pool to 64 graphs.
// Dtype-adaptive: on-device sniff decides fp32-vs-bf16 (floats) and
// int32-vs-int64 (indices); all IO goes through flag-dispatched helpers.
// CSR-by-dst built once; aggregation is atomic-free gather. NaN diagnostics
// encoded into the output if anything goes wrong.

#define NN 100000
#define NE 3200000
#define NF 128
#define NH 16
#define NO 2
#define NG 64
#define NBLK 391  // ceil(NN/256)

// ---------------- dtype-dispatched IO helpers ----------------

__device__ __forceinline__ float ldf(const void* p, int i, int f32) {
  if (f32) return ((const float*)p)[i];
  unsigned int u = ((const unsigned short*)p)[i];
  return __uint_as_float(u << 16);
}
__device__ __forceinline__ int ldi(const void* p, int i, int i64) {
  if (i64) return (int)((const long long*)p)[i];
  return ((const int*)p)[i];
}
__device__ __forceinline__ void stf(void* p, int i, float v, int f32) {
  if (f32) {
    ((float*)p)[i] = v;
  } else {
    unsigned int w = __float_as_uint(v);
    unsigned int r = (w + 0x7fffu + ((w >> 16) & 1u)) >> 16;  // RNE bf16
    ((unsigned short*)p)[i] = (unsigned short)r;
  }
}
__device__ __forceinline__ int okf(float v) { return (v == v) && (fabsf(v) < 1e30f); }
__device__ __forceinline__ void nflag(int* diag, int bad, int bit) {
  if (__any(bad)) {
    if ((threadIdx.x & 63) == 0) atomicOr(diag + 2, 1 << bit);
  }
}
__device__ __forceinline__ int clampi(int v, int hi) {
  return (unsigned)v < (unsigned)hi ? v : 0;
}

// ---------------- dtype sniff ----------------

// diag[0] = floats-are-fp32, diag[1] = ints-are-int64, diag[2] = NaN stage bitmap
__global__ __launch_bounds__(64) void k_sniff(const void* x, const void* ei, int* diag) {
  if (threadIdx.x != 0) return;
  const unsigned int* xw = (const unsigned int*)x;
  int hits = 0;
  for (int i = 0; i < 64; ++i) {
    unsigned int e = (xw[i] >> 7) & 0xffu;  // exponent of the LOW half-word as bf16
    if (e >= 116u && e <= 133u) hits++;     // N(0,1) bf16 lands here ~100%; random bits ~7%
  }
  diag[0] = (hits < 32) ? 1 : 0;
  const unsigned int* ew = (const unsigned int*)ei;
  int nz = 0;
  for (int i = 0; i < 64; ++i) nz += (ew[2 * i + 1] != 0u);  // int64 high words are all 0
  diag[1] = (nz == 0) ? 1 : 0;
}

// ---------------- degree / CSR build ----------------

__global__ __launch_bounds__(256) void k_hist(const void* ei, const int* __restrict__ diag,
                                              int* __restrict__ cnt) {
  int e = blockIdx.x * 256 + threadIdx.x;
  if (e >= NE) return;
  int i64 = diag[1];
  int d = clampi(ldi(ei, NE + e, i64), NN);
  atomicAdd(&cnt[d], 1);
}

__global__ __launch_bounds__(256) void k_dinv(const int* __restrict__ cnt, float* __restrict__ dinv) {
  int i = blockIdx.x * 256 + threadIdx.x;
  if (i < NN) {
    int c = cnt[i];
    c = c < 0 ? 0 : c;
    dinv[i] = rsqrtf((float)(c + 1));  // +1 self loop, always >= 1
  }
}

__global__ __launch_bounds__(256) void k_scan1(const int* __restrict__ cnt, int* __restrict__ rowstart,
                                               int* __restrict__ bsums) {
  __shared__ int s[256];
  int tid = threadIdx.x;
  int i = blockIdx.x * 256 + tid;
  int v = (i < NN) ? cnt[i] : 0;
  s[tid] = v;
  __syncthreads();
  for (int off = 1; off < 256; off <<= 1) {
    int t = (tid >= off) ? s[tid - off] : 0;
    __syncthreads();
    s[tid] += t;
    __syncthreads();
  }
  if (i < NN) rowstart[i] = s[tid] - v;
  if (tid == 255) bsums[blockIdx.x] = s[tid];
}

__global__ __launch_bounds__(512) void k_scan2(int* __restrict__ bsums) {
  __shared__ int s[512];
  int tid = threadIdx.x;
  int v = (tid < NBLK) ? bsums[tid] : 0;
  s[tid] = v;
  __syncthreads();
  for (int off = 1; off < 512; off <<= 1) {
    int t = (tid >= off) ? s[tid - off] : 0;
    __syncthreads();
    s[tid] += t;
    __syncthreads();
  }
  if (tid < NBLK) bsums[tid] = s[tid] - v;
}

__global__ __launch_bounds__(256) void k_scan3(int* __restrict__ rowstart, int* __restrict__ cursor,
                                               const int* __restrict__ bsums) {
  int i = blockIdx.x * 256 + threadIdx.x;
  if (i < NN) {
    int r = rowstart[i] + bsums[blockIdx.x];
    rowstart[i] = r;
    cursor[i] = r;
  }
  if (i == 0) rowstart[NN] = NE;
}

__global__ __launch_bounds__(256) void k_scatter_csr(const void* ei, const int* __restrict__ diag,
                                                     int* __restrict__ cursor, int* __restrict__ srcs) {
  int e = blockIdx.x * 256 + threadIdx.x;
  if (e >= NE) return;
  int i64 = diag[1];
  int s = clampi(ldi(ei, e, i64), NN);
  int d = clampi(ldi(ei, NE + e, i64), NN);
  int pos = atomicAdd(&cursor[d], 1);
  if (pos >= 0 && pos < NE) srcs[pos] = s;
}

// ---------------- dense transforms ----------------

// x[NN,128] @ W0[128,16] -> out[NN,16] fp32. Block = 16 nodes x 16 feats.
__global__ __launch_bounds__(256) void k_t0(const void* __restrict__ x, const void* __restrict__ W0,
                                            int* __restrict__ diag, float* __restrict__ out) {
  __shared__ float ws[NF * NH];
  __shared__ float xs[16 * 129];
  int tid = threadIdx.x;
  int f32 = diag[0];
  int node0 = blockIdx.x * 16;  // NN % 16 == 0
#pragma unroll
  for (int r = 0; r < 8; ++r) ws[tid + 256 * r] = ldf(W0, tid + 256 * r, f32);
#pragma unroll
  for (int r = 0; r < 8; ++r) {
    int idx = tid + 256 * r;
    int row = idx >> 7, col = idx & 127;
    xs[row * 129 + col] = ldf(x, (node0 + row) * NF + col, f32);
  }
  __syncthreads();
  int nl = tid >> 4, f = tid & 15;
  float acc = 0.f;
#pragma unroll 4
  for (int k = 0; k < NF; ++k) acc += xs[nl * 129 + k] * ws[k * NH + f];
  out[(node0 + nl) * NH + f] = acc;
  nflag(diag, !okf(acc), 0);  // stage 1
}

__global__ __launch_bounds__(256) void k_t16(const float* __restrict__ h, const void* __restrict__ W,
                                             int* __restrict__ diag, int bit, float* __restrict__ out) {
  __shared__ float ws[NH * NH];
  __shared__ float xs[256];
  int tid = threadIdx.x;
  int f32 = diag[0];
  ws[tid] = ldf(W, tid, f32);
  int base = blockIdx.x * 256;  // 1.6M / 256 exact
  xs[tid] = h[base + tid];
  __syncthreads();
  int nl = tid >> 4, f = tid & 15;
  float acc = 0.f;
#pragma unroll
  for (int k = 0; k < NH; ++k) acc += xs[nl * NH + k] * ws[k * NH + f];
  out[base + tid] = acc;
  nflag(diag, !okf(acc), bit);
}

__global__ __launch_bounds__(256) void k_t3(const float* __restrict__ h, const void* __restrict__ W3,
                                            int* __restrict__ diag, float* __restrict__ out) {
  __shared__ float ws[NH * NO];
  int tid = threadIdx.x;
  int f32 = diag[0];
  if (tid < NH * NO) ws[tid] = ldf(W3, tid, f32);
  __syncthreads();
  int node = blockIdx.x * 256 + tid;
  if (node >= NN) return;
  const float4* hp = (const float4*)(h + node * NH);
  float a0 = 0.f, a1 = 0.f;
#pragma unroll
  for (int q = 0; q < 4; ++q) {
    float4 v = hp[q];
    a0 += v.x * ws[(q * 4 + 0) * 2] + v.y * ws[(q * 4 + 1) * 2] +
          v.z * ws[(q * 4 + 2) * 2] + v.w * ws[(q * 4 + 3) * 2];
    a1 += v.x * ws[(q * 4 + 0) * 2 + 1] + v.y * ws[(q * 4 + 1) * 2 + 1] +
          v.z * ws[(q * 4 + 2) * 2 + 1] + v.w * ws[(q * 4 + 3) * 2 + 1];
  }
  ((float2*)out)[node] = make_float2(a0, a1);
  nflag(diag, !okf(a0) || !okf(a1), 6);  // stage 7
}

// ---------------- aggregation (gather over CSR) ----------------

// out[i][f] = dinv[i]*sum_e dinv[s_e]*hin[s_e][f] + dinv[i]^2*hin[i][f] + b[f] (+PReLU)
__global__ __launch_bounds__(256) void k_agg16(const float* __restrict__ hin,
                                               const int* __restrict__ srcs,
                                               const int* __restrict__ rowstart,
                                               const float* __restrict__ dinv,
                                               const void* __restrict__ b, const void* __restrict__ a,
                                               int prelu, int* __restrict__ diag, int bit,
                                               float* __restrict__ hout) {
  int gid = blockIdx.x * 256 + threadIdx.x;
  int node = gid >> 4, f = gid & 15;
  int f32 = diag[0];
  float dv = dinv[node];
  float acc = 0.f;
  int e0 = rowstart[node], e1 = rowstart[node + 1];
  for (int e = e0; e < e1; ++e) {
    int s = srcs[e];  // broadcast across the node's 16 feat-threads
    acc += dinv[s] * hin[s * NH + f];
  }
  acc = dv * acc + dv * dv * hin[gid] + ldf(b, f, f32);
  if (prelu) {
    float av = ldf(a, 0, f32);
    acc = acc > 0.f ? acc : av * acc;
  }
  hout[gid] = acc;
  nflag(diag, !okf(acc), bit);
}

__global__ __launch_bounds__(256) void k_agg2(const float* __restrict__ tin,
                                              const int* __restrict__ srcs,
                                              const int* __restrict__ rowstart,
                                              const float* __restrict__ dinv,
                                              const void* __restrict__ b3,
                                              int* __restrict__ diag, float* __restrict__ out) {
  int node = blockIdx.x * 256 + threadIdx.x;
  if (node >= NN) return;
  int f32 = diag[0];
  float dv = dinv[node];
  float a0 = 0.f, a1 = 0.f;
  int e0 = rowstart[node], e1 = rowstart[node + 1];
  for (int e = e0; e < e1; ++e) {
    int s = srcs[e];
    float ds = dinv[s];
    float2 hv = ((const float2*)tin)[s];
    a0 += ds * hv.x;
    a1 += ds * hv.y;
  }
  float2 t = ((const float2*)tin)[node];
  a0 = dv * a0 + dv * dv * t.x + ldf(b3, 0, f32);
  a1 = dv * a1 + dv * dv * t.y + ldf(b3, 1, f32);
  ((float2*)out)[node] = make_float2(a0, a1);
  nflag(diag, !okf(a0) || !okf(a1), 7);  // stage 8
}

// ---------------- pooling ----------------

__global__ __launch_bounds__(256) void k_pool(const float* __restrict__ h, const void* __restrict__ batch,
                                              const int* __restrict__ diag, float* __restrict__ pool) {
  __shared__ float ssum[NG * NO];
  __shared__ float scnt[NG];
  int tid = threadIdx.x;
  if (tid < NG * NO) ssum[tid] = 0.f;
  if (tid < NG) scnt[tid] = 0.f;
  __syncthreads();
  int i = blockIdx.x * 256 + tid;
  if (i < NN) {
    int i64 = diag[1];
    int g = ldi(batch, i, i64);
    g = (unsigned)g < NG ? g : 0;
    float2 v = ((const float2*)h)[i];
    atomicAdd(&ssum[g * 2], v.x);
    atomicAdd(&ssum[g * 2 + 1], v.y);
    atomicAdd(&scnt[g], 1.f);
  }
  __syncthreads();
  if (tid < NG * NO && ssum[tid] != 0.f) atomicAdd(&pool[tid], ssum[tid]);
  if (tid < NG && scnt[tid] != 0.f) atomicAdd(&pool[NG * NO + tid], scnt[tid]);
}

// On failure, encodes diagnostics: out = 1024 + first_nan_stage*64 + f32*16 + i64*8
__global__ __launch_bounds__(128) void k_final(const float* __restrict__ pool,
                                               const int* __restrict__ diag, void* __restrict__ out) {
  int i = threadIdx.x;
  int f32 = diag[0], i64 = diag[1], stg = diag[2];
  float c = pool[NG * NO + (i >> 1)];
  c = c > 1.f ? c : 1.f;
  float v = pool[i] / c;
  if (stg != 0 || !okf(v)) {
    int stage = stg ? __ffs(stg) : 15;
    v = 1024.0f + stage * 64.0f + f32 * 16.0f + i64 * 8.0f;
  }
  stf(out, i, v, f32);
}

__global__ __launch_bounds__(128) void k_diag_ws(void* out, float v) {
  // bf16-encode ws_size; huge value, distinguishable from codes (<2048) and answers (<1)
  unsigned int w = __float_as_uint(v);
  ((unsigned short*)out)[threadIdx.x] = (unsigned short)(w >> 16);
}

// ---------------- launch ----------------

extern "C" void kernel_launch(void* const* d_in, const int* in_sizes, int n_in,
                              void* d_out, int out_size, void* d_ws, size_t ws_size,
                              hipStream_t stream) {
  const void* x  = d_in[0];
  const void* ei = d_in[1];
  const void* batch = d_in[2];
  const void* W0 = d_in[3];
  const void* b0 = d_in[4];
  const void* a0 = d_in[5];
  const void* W1 = d_in[6];
  const void* b1 = d_in[7];
  const void* a1 = d_in[8];
  const void* W2 = d_in[9];
  const void* b2 = d_in[10];
  const void* a2 = d_in[11];
  const void* W3 = d_in[12];
  const void* b3 = d_in[13];

  // layout (bytes), all 64B-aligned chunks
  char* w = (char*)d_ws;
  int* cnt      = (int*)(w + 0);           // 400000
  float* pool   = (float*)(w + 400000);    // 768
  int* diag     = (int*)(w + 400768);      // 64
  float* dinv   = (float*)(w + 400832);    // 400000
  int* rowstart = (int*)(w + 800832);      // 400004 -> pad 400064
  int* cursor   = (int*)(w + 1200896);     // 400000
  int* bsums    = (int*)(w + 1600896);     // 2048
  int* srcs     = (int*)(w + 1602944);     // 12800000
  float* bufA   = (float*)(w + 14402944);  // 6400000
  float* bufB   = (float*)(w + 20802944);  // 6400000
  float* t3buf  = (float*)(w + 27202944);  // 800000 -> end 28002944
  const size_t NEED = 28002944;

  if (ws_size < NEED) {
    k_diag_ws<<<1, 128, 0, stream>>>(d_out, (float)ws_size);
    return;
  }

  hipMemsetAsync(d_ws, 0, 400832, stream);  // cnt + pool + diag

  k_sniff<<<1, 64, 0, stream>>>(x, ei, diag);

  k_hist<<<NE / 256, 256, 0, stream>>>(ei, diag, cnt);
  k_dinv<<<NBLK, 256, 0, stream>>>(cnt, dinv);
  k_scan1<<<NBLK, 256, 0, stream>>>(cnt, rowstart, bsums);
  k_scan2<<<1, 512, 0, stream>>>(bsums);
  k_scan3<<<NBLK, 256, 0, stream>>>(rowstart, cursor, bsums);
  k_scatter_csr<<<NE / 256, 256, 0, stream>>>(ei, diag, cursor, srcs);

  k_t0<<<NN / 16, 256, 0, stream>>>(x, W0, diag, bufA);
  k_agg16<<<NN * NH / 256, 256, 0, stream>>>(bufA, srcs, rowstart, dinv, b0, a0, 1, diag, 1, bufB);
  k_t16<<<NN * NH / 256, 256, 0, stream>>>(bufB, W1, diag, 2, bufA);
  k_agg16<<<NN * NH / 256, 256, 0, stream>>>(bufA, srcs, rowstart, dinv, b1, a1, 1, diag, 3, bufB);
  k_t16<<<NN * NH / 256, 256, 0, stream>>>(bufB, W2, diag, 4, bufA);
  k_agg16<<<NN * NH / 256, 256, 0, stream>>>(bufA, srcs, rowstart, dinv, b2, a2, 1, diag, 5, bufB);
  k_t3<<<NBLK, 256, 0, stream>>>(bufB, W3, diag, t3buf);
  k_agg2<<<NBLK, 256, 0, stream>>>(t3buf, srcs, rowstart, dinv, b3, diag, bufA);

  k_pool<<<NBLK, 256, 0, stream>>>(bufA, batch, diag, pool);
  k_final<<<1, 128, 0, stream>>>(pool, diag, d_out);
}

// Round 4
// 551.538 us; speedup vs baseline: 1.6465x; 1.6465x over previous
//
#include <hip/hip_runtime.h>

// GCN: 100K nodes, 3.2M edges, 128 -> 16 -> 16 -> 16 -> 2, mean-pool to 64 graphs.
// R4: CSR build via deterministic two-level bucket sort (no global atomics,
// coalesced writes); dinv pre-scaling folded into transforms so the agg inner
// loop is a single gather stream. Dtype-adaptive IO (fp32/bf16, int32/int64).

#define NN 100000
#define NE 3200000
#define NF 128
#define NH 16
#define NO 2
#define NG 64
#define NBLK 391        // ceil(NN/256)
#define NBUK 782        // ceil(NN/128), bucket = dst >> 7
#define CHUNK 4096
#define NBLKA 782       // ceil(NE/CHUNK)
#define CAP 5120        // max edges/bucket in k_bsort (avg 4093, 5-sigma ~4400)

// ---------------- dtype-dispatched IO helpers ----------------

__device__ __forceinline__ float ldf(const void* p, int i, int f32) {
  if (f32) return ((const float*)p)[i];
  unsigned int u = ((const unsigned short*)p)[i];
  return __uint_as_float(u << 16);
}
__device__ __forceinline__ int ldi(const void* p, int i, int i64) {
  if (i64) return (int)((const long long*)p)[i];
  return ((const int*)p)[i];
}
__device__ __forceinline__ void stf(void* p, int i, float v, int f32) {
  if (f32) {
    ((float*)p)[i] = v;
  } else {
    unsigned int w = __float_as_uint(v);
    unsigned int r = (w + 0x7fffu + ((w >> 16) & 1u)) >> 16;  // RNE bf16
    ((unsigned short*)p)[i] = (unsigned short)r;
  }
}
__device__ __forceinline__ int okf(float v) { return (v == v) && (fabsf(v) < 1e30f); }
__device__ __forceinline__ void nflag(int* diag, int bad, int bit) {
  if (__any(bad)) {
    if ((threadIdx.x & 63) == 0) atomicOr(diag + 2, 1 << bit);
  }
}
__device__ __forceinline__ int clampi(int v, int hi) {
  return (unsigned)v < (unsigned)hi ? v : 0;
}

// ---------------- dtype sniff ----------------

// diag[0]=floats-are-fp32, diag[1]=ints-are-int64, diag[2]=error stage bitmap
__global__ __launch_bounds__(64) void k_sniff(const void* x, const void* ei, int* diag) {
  if (threadIdx.x != 0) return;
  const unsigned int* xw = (const unsigned int*)x;
  int hits = 0;
  for (int i = 0; i < 64; ++i) {
    unsigned int e = (xw[i] >> 7) & 0xffu;
    if (e >= 116u && e <= 133u) hits++;
  }
  diag[0] = (hits < 32) ? 1 : 0;
  const unsigned int* ew = (const unsigned int*)ei;
  int nz = 0;
  for (int i = 0; i < 64; ++i) nz += (ew[2 * i + 1] != 0u);
  diag[1] = (nz == 0) ? 1 : 0;
}

// ---------------- CSR build: two-level bucket sort ----------------

// Pass 1: per-block bucket histogram -> matrix[blk][b] (coalesced row write)
__global__ __launch_bounds__(256) void k_count(const void* ei, const int* __restrict__ diag,
                                               int* __restrict__ matrix) {
  __shared__ int lh[NBUK];
  int tid = threadIdx.x, blk = blockIdx.x;
  for (int b = tid; b < NBUK; b += 256) lh[b] = 0;
  __syncthreads();
  int i64 = diag[1];
  int base = blk * CHUNK;
  int n = NE - base; n = n > CHUNK ? CHUNK : n;
  for (int i = tid; i < n; i += 256) {
    int d = clampi(ldi(ei, NE + base + i, i64), NN);
    atomicAdd(&lh[d >> 7], 1);
  }
  __syncthreads();
  for (int b = tid; b < NBUK; b += 256) matrix[blk * NBUK + b] = lh[b];
}

// Pass 2: per-bucket column scan over blocks; totals -> bucket_start[b] (raw)
__global__ __launch_bounds__(256) void k_rowscan(int* __restrict__ matrix, int* __restrict__ bucket_start) {
  __shared__ int s[1024];
  int tid = threadIdx.x, b = blockIdx.x;
#pragma unroll
  for (int k = 0; k < 4; ++k) {
    int i = tid + 256 * k;
    s[i] = (i < NBLKA) ? matrix[i * NBUK + b] : 0;
  }
  __syncthreads();
  for (int off = 1; off < 1024; off <<= 1) {
    int v[4];
#pragma unroll
    for (int k = 0; k < 4; ++k) { int i = tid + 256 * k; v[k] = (i >= off) ? s[i - off] : 0; }
    __syncthreads();
#pragma unroll
    for (int k = 0; k < 4; ++k) s[tid + 256 * k] += v[k];
    __syncthreads();
  }
#pragma unroll
  for (int k = 0; k < 4; ++k) {
    int i = tid + 256 * k;
    if (i < NBLKA) matrix[i * NBUK + b] = (i > 0) ? s[i - 1] : 0;  // exclusive over blocks
  }
  if (tid == 0) bucket_start[b] = s[1023];  // bucket total
}

// Pass 3: scan bucket totals -> bucket_start (exclusive); rowstart[NN]=NE
__global__ __launch_bounds__(1024) void k_sscan(int* __restrict__ bucket_start, int* __restrict__ rowstart) {
  __shared__ int s[1024];
  int tid = threadIdx.x;
  s[tid] = (tid < NBUK) ? bucket_start[tid] : 0;
  __syncthreads();
  for (int off = 1; off < 1024; off <<= 1) {
    int v = (tid >= off) ? s[tid - off] : 0;
    __syncthreads();
    s[tid] += v;
    __syncthreads();
  }
  if (tid < NBUK) bucket_start[tid] = (tid > 0) ? s[tid - 1] : 0;
  if (tid == 0) { bucket_start[NBUK] = s[1023]; rowstart[NN] = NE; }
}

// Pass 4: scatter edges into bucketed array (packed (dst&127)<<17 | src),
// block-locally sorted in LDS so global writes are coalesced runs.
__global__ __launch_bounds__(256) void k_bscatter(const void* ei, const int* __restrict__ diag,
                                                  const int* __restrict__ matrix,
                                                  const int* __restrict__ bucket_start,
                                                  int* __restrict__ ents) {
  __shared__ int ssrc[CHUNK];
  __shared__ int sdst[CHUNK];
  __shared__ int spkt[CHUNK];
  __shared__ int gpos[CHUNK];
  __shared__ int lhist[1024];   // padded for scan
  __shared__ int lcur[NBUK];
  __shared__ int goff[NBUK];
  int tid = threadIdx.x, blk = blockIdx.x;
#pragma unroll
  for (int k = 0; k < 4; ++k) lhist[tid + 256 * k] = 0;
  __syncthreads();
  int i64 = diag[1];
  int base = blk * CHUNK;
  int n = NE - base; n = n > CHUNK ? CHUNK : n;
  for (int i = tid; i < n; i += 256) {
    int sv = clampi(ldi(ei, base + i, i64), NN);
    int dv = clampi(ldi(ei, NE + base + i, i64), NN);
    ssrc[i] = sv; sdst[i] = dv;
    atomicAdd(&lhist[dv >> 7], 1);
  }
  __syncthreads();
  // inclusive scan of lhist[0..1023]
  for (int off = 1; off < 1024; off <<= 1) {
    int v[4];
#pragma unroll
    for (int k = 0; k < 4; ++k) { int i = tid + 256 * k; v[k] = (i >= off) ? lhist[i - off] : 0; }
    __syncthreads();
#pragma unroll
    for (int k = 0; k < 4; ++k) lhist[tid + 256 * k] += v[k];
    __syncthreads();
  }
  // excl[b] = lhist[b-1]; goff[b] = bucket_start[b] + matrix[blk][b] - excl[b]; lcur=excl
  for (int b = tid; b < NBUK; b += 256) {
    int excl = (b > 0) ? lhist[b - 1] : 0;
    lcur[b] = excl;
    goff[b] = bucket_start[b] + matrix[blk * NBUK + b] - excl;
  }
  __syncthreads();
  for (int i = tid; i < n; i += 256) {
    int dv = sdst[i], b = dv >> 7;
    int r = atomicAdd(&lcur[b], 1);
    spkt[r] = ((dv & 127) << 17) | ssrc[i];
    gpos[r] = goff[b] + r;
  }
  __syncthreads();
  for (int i = tid; i < n; i += 256) ents[gpos[i]] = spkt[i];  // coalesced runs
}

// Pass 5: per-bucket counting sort -> in-place CSR srcs; emits rowstart + dinv.
__global__ __launch_bounds__(256) void k_bsort(int* __restrict__ ents, const int* __restrict__ bucket_start,
                                               int* __restrict__ rowstart, float* __restrict__ dinv,
                                               int* __restrict__ diag) {
  __shared__ int ent[CAP];
  __shared__ int sorted[CAP];
  __shared__ int lh[128];
  __shared__ int lcur[128];
  int tid = threadIdx.x, b = blockIdx.x;
  int bs = bucket_start[b], be = bucket_start[b + 1];
  int n = be - bs;
  if (n > CAP) { n = CAP; if (tid == 0) atomicOr(diag + 2, 1 << 9); }
  for (int i = tid; i < n; i += 256) ent[i] = ents[bs + i];
  if (tid < 128) lh[tid] = 0;
  __syncthreads();
  for (int i = tid; i < n; i += 256) atomicAdd(&lh[ent[i] >> 17], 1);
  __syncthreads();
  int node0 = b << 7;
  int nn = NN - node0; nn = nn > 128 ? 128 : nn;
  int myc = (tid < 128) ? lh[tid] : 0;
  // inclusive scan over 128
  for (int off = 1; off < 128; off <<= 1) {
    int v = 0;
    if (tid < 128 && tid >= off) v = lh[tid - off];
    __syncthreads();
    if (tid < 128) lh[tid] += v;
    __syncthreads();
  }
  if (tid < 128) {
    int excl = (tid > 0) ? lh[tid - 1] : 0;
    lcur[tid] = excl;
    if (tid < nn) {
      rowstart[node0 + tid] = bs + excl;
      dinv[node0 + tid] = rsqrtf((float)(myc + 1));
    }
  }
  __syncthreads();
  for (int i = tid; i < n; i += 256) {
    int e = ent[i];
    int r = atomicAdd(&lcur[e >> 17], 1);
    sorted[r] = e & 0x1FFFF;
  }
  __syncthreads();
  for (int i = tid; i < n; i += 256) ents[bs + i] = sorted[i];  // in-place, coalesced
}

// ---------------- dense transforms (outputs pre-scaled by dinv[row]) ----------------

__global__ __launch_bounds__(256) void k_t0(const void* __restrict__ x, const void* __restrict__ W0,
                                            const float* __restrict__ dinv,
                                            int* __restrict__ diag, float* __restrict__ out) {
  __shared__ float ws[NF * NH];
  __shared__ float xs[16 * 129];
  int tid = threadIdx.x;
  int f32 = diag[0];
  int node0 = blockIdx.x * 16;
#pragma unroll
  for (int r = 0; r < 8; ++r) ws[tid + 256 * r] = ldf(W0, tid + 256 * r, f32);
#pragma unroll
  for (int r = 0; r < 8; ++r) {
    int idx = tid + 256 * r;
    int row = idx >> 7, col = idx & 127;
    xs[row * 129 + col] = ldf(x, (node0 + row) * NF + col, f32);
  }
  __syncthreads();
  int nl = tid >> 4, f = tid & 15;
  float acc = 0.f;
#pragma unroll 4
  for (int k = 0; k < NF; ++k) acc += xs[nl * 129 + k] * ws[k * NH + f];
  acc *= dinv[node0 + nl];
  out[(node0 + nl) * NH + f] = acc;
  nflag(diag, !okf(acc), 0);
}

__global__ __launch_bounds__(256) void k_t16(const float* __restrict__ h, const void* __restrict__ W,
                                             const float* __restrict__ dinv,
                                             int* __restrict__ diag, int bit, float* __restrict__ out) {
  __shared__ float ws[NH * NH];
  __shared__ float xs[256];
  int tid = threadIdx.x;
  int f32 = diag[0];
  ws[tid] = ldf(W, tid, f32);
  int base = blockIdx.x * 256;
  xs[tid] = h[base + tid];
  __syncthreads();
  int nl = tid >> 4, f = tid & 15;
  float acc = 0.f;
#pragma unroll
  for (int k = 0; k < NH; ++k) acc += xs[nl * NH + k] * ws[k * NH + f];
  acc *= dinv[(base >> 4) + nl];
  out[base + tid] = acc;
  nflag(diag, !okf(acc), bit);
}

__global__ __launch_bounds__(256) void k_t3(const float* __restrict__ h, const void* __restrict__ W3,
                                            const float* __restrict__ dinv,
                                            int* __restrict__ diag, float* __restrict__ out) {
  __shared__ float ws[NH * NO];
  int tid = threadIdx.x;
  int f32 = diag[0];
  if (tid < NH * NO) ws[tid] = ldf(W3, tid, f32);
  __syncthreads();
  int node = blockIdx.x * 256 + tid;
  if (node >= NN) return;
  const float4* hp = (const float4*)(h + node * NH);
  float a0 = 0.f, a1 = 0.f;
#pragma unroll
  for (int q = 0; q < 4; ++q) {
    float4 v = hp[q];
    a0 += v.x * ws[(q * 4 + 0) * 2] + v.y * ws[(q * 4 + 1) * 2] +
          v.z * ws[(q * 4 + 2) * 2] + v.w * ws[(q * 4 + 3) * 2];
    a1 += v.x * ws[(q * 4 + 0) * 2 + 1] + v.y * ws[(q * 4 + 1) * 2 + 1] +
          v.z * ws[(q * 4 + 2) * 2 + 1] + v.w * ws[(q * 4 + 3) * 2 + 1];
  }
  float dv = dinv[node];
  ((float2*)out)[node] = make_float2(a0 * dv, a1 * dv);
  nflag(diag, !okf(a0) || !okf(a1), 6);
}

// ---------------- aggregation (single gather stream; input pre-scaled) ----------------

// out[i][f] = dinv[i]*(sum_e hs[src_e][f] + hs[i][f]) + b[f]  (+PReLU)
__global__ __launch_bounds__(256) void k_agg16(const float* __restrict__ hin,
                                               const int* __restrict__ srcs,
                                               const int* __restrict__ rowstart,
                                               const float* __restrict__ dinv,
                                               const void* __restrict__ b, const void* __restrict__ a,
                                               int prelu, int* __restrict__ diag, int bit,
                                               float* __restrict__ hout) {
  int gid = blockIdx.x * 256 + threadIdx.x;
  int node = gid >> 4, f = gid & 15;
  int f32 = diag[0];
  float acc = hin[gid];  // self term hs[i][f]
  int e0 = rowstart[node], e1 = rowstart[node + 1];
  for (int e = e0; e < e1; ++e) {
    int s = srcs[e];
    s = (unsigned)s < NN ? s : 0;  // safety vs (impossible) bucket overflow
    acc += hin[s * NH + f];
  }
  acc = dinv[node] * acc + ldf(b, f, f32);
  if (prelu) {
    float av = ldf(a, 0, f32);
    acc = acc > 0.f ? acc : av * acc;
  }
  hout[gid] = acc;
  nflag(diag, !okf(acc), bit);
}

__global__ __launch_bounds__(256) void k_agg2(const float* __restrict__ tin,
                                              const int* __restrict__ srcs,
                                              const int* __restrict__ rowstart,
                                              const float* __restrict__ dinv,
                                              const void* __restrict__ b3,
                                              int* __restrict__ diag, float* __restrict__ out) {
  int node = blockIdx.x * 256 + threadIdx.x;
  if (node >= NN) return;
  int f32 = diag[0];
  float2 t = ((const float2*)tin)[node];
  float a0 = t.x, a1 = t.y;
  int e0 = rowstart[node], e1 = rowstart[node + 1];
  for (int e = e0; e < e1; ++e) {
    int s = srcs[e];
    s = (unsigned)s < NN ? s : 0;
    float2 hv = ((const float2*)tin)[s];
    a0 += hv.x;
    a1 += hv.y;
  }
  float dv = dinv[node];
  a0 = dv * a0 + ldf(b3, 0, f32);
  a1 = dv * a1 + ldf(b3, 1, f32);
  ((float2*)out)[node] = make_float2(a0, a1);
  nflag(diag, !okf(a0) || !okf(a1), 7);
}

// ---------------- pooling ----------------

__global__ __launch_bounds__(256) void k_pool(const float* __restrict__ h, const void* __restrict__ batch,
                                              const int* __restrict__ diag, float* __restrict__ pool) {
  __shared__ float ssum[NG * NO];
  __shared__ float scnt[NG];
  int tid = threadIdx.x;
  if (tid < NG * NO) ssum[tid] = 0.f;
  if (tid < NG) scnt[tid] = 0.f;
  __syncthreads();
  int i = blockIdx.x * 256 + tid;
  if (i < NN) {
    int i64 = diag[1];
    int g = ldi(batch, i, i64);
    g = (unsigned)g < NG ? g : 0;
    float2 v = ((const float2*)h)[i];
    atomicAdd(&ssum[g * 2], v.x);
    atomicAdd(&ssum[g * 2 + 1], v.y);
    atomicAdd(&scnt[g], 1.f);
  }
  __syncthreads();
  if (tid < NG * NO && ssum[tid] != 0.f) atomicAdd(&pool[tid], ssum[tid]);
  if (tid < NG && scnt[tid] != 0.f) atomicAdd(&pool[NG * NO + tid], scnt[tid]);
}

__global__ __launch_bounds__(128) void k_final(const float* __restrict__ pool,
                                               const int* __restrict__ diag, void* __restrict__ out) {
  int i = threadIdx.x;
  int f32 = diag[0], i64 = diag[1], stg = diag[2];
  float c = pool[NG * NO + (i >> 1)];
  c = c > 1.f ? c : 1.f;
  float v = pool[i] / c;
  if (stg != 0 || !okf(v)) {
    int stage = stg ? __ffs(stg) : 15;
    v = 1024.0f + stage * 64.0f + f32 * 16.0f + i64 * 8.0f;
  }
  stf(out, i, v, f32);
}

__global__ __launch_bounds__(128) void k_diag_ws(void* out, float v) {
  unsigned int w = __float_as_uint(v);
  ((unsigned short*)out)[threadIdx.x] = (unsigned short)(w >> 16);
}

// ---------------- launch ----------------

extern "C" void kernel_launch(void* const* d_in, const int* in_sizes, int n_in,
                              void* d_out, int out_size, void* d_ws, size_t ws_size,
                              hipStream_t stream) {
  const void* x  = d_in[0];
  const void* ei = d_in[1];
  const void* batch = d_in[2];
  const void* W0 = d_in[3];
  const void* b0 = d_in[4];
  const void* a0 = d_in[5];
  const void* W1 = d_in[6];
  const void* b1 = d_in[7];
  const void* a1 = d_in[8];
  const void* W2 = d_in[9];
  const void* b2 = d_in[10];
  const void* a2 = d_in[11];
  const void* W3 = d_in[12];
  const void* b3 = d_in[13];

  // workspace layout (bytes)
  char* w = (char*)d_ws;
  int* diag         = (int*)(w + 0);          // 64
  float* pool       = (float*)(w + 64);       // 768 -> 832, pad 896
  float* dinv       = (float*)(w + 896);      // 400000 -> 400896, pad 400960
  int* rowstart     = (int*)(w + 400960);     // 400004 -> pad 801088
  int* bucket_start = (int*)(w + 801088);     // 783*4=3132 -> pad 804288
  int* ents         = (int*)(w + 804288);     // 12.8MB -> 13604288   (becomes CSR srcs)
  float* bufB       = (float*)(w + 13604288); // 6.4MB -> 20004288
  float* bufA       = (float*)(w + 20004288); // 6.4MB -> 26404288
  // overlays inside bufA (disjoint lifetimes):
  int* matrix = (int*)bufA;                       // 782*782*4 = 2446096, dead before k_t0
  float* t3buf = (float*)bufA;                    // 800000, live only for t3/agg2
  float* out2  = (float*)(w + 20004288 + 1048576); // 800000, agg2 output
  const size_t NEED = 26404288;

  if (ws_size < NEED) {
    k_diag_ws<<<1, 128, 0, stream>>>(d_out, (float)ws_size);
    return;
  }

  hipMemsetAsync(d_ws, 0, 832, stream);  // diag + pool

  k_sniff<<<1, 64, 0, stream>>>(x, ei, diag);

  // CSR build (deterministic bucket sort)
  k_count<<<NBLKA, 256, 0, stream>>>(ei, diag, matrix);
  k_rowscan<<<NBUK, 256, 0, stream>>>(matrix, bucket_start);
  k_sscan<<<1, 1024, 0, stream>>>(bucket_start, rowstart);
  k_bscatter<<<NBLKA, 256, 0, stream>>>(ei, diag, matrix, bucket_start, ents);
  k_bsort<<<NBUK, 256, 0, stream>>>(ents, bucket_start, rowstart, dinv, diag);

  // layers (transforms pre-scale rows by dinv)
  k_t0<<<NN / 16, 256, 0, stream>>>(x, W0, dinv, diag, bufA);
  k_agg16<<<NN * NH / 256, 256, 0, stream>>>(bufA, ents, rowstart, dinv, b0, a0, 1, diag, 1, bufB);
  k_t16<<<NN * NH / 256, 256, 0, stream>>>(bufB, W1, dinv, diag, 2, bufA);
  k_agg16<<<NN * NH / 256, 256, 0, stream>>>(bufA, ents, rowstart, dinv, b1, a1, 1, diag, 3, bufB);
  k_t16<<<NN * NH / 256, 256, 0, stream>>>(bufB, W2, dinv, diag, 4, bufA);
  k_agg16<<<NN * NH / 256, 256, 0, stream>>>(bufA, ents, rowstart, dinv, b2, a2, 1, diag, 5, bufB);
  k_t3<<<NBLK, 256, 0, stream>>>(bufB, W3, dinv, diag, t3buf);
  k_agg2<<<NBLK, 256, 0, stream>>>(t3buf, ents, rowstart, dinv, b3, diag, out2);

  k_pool<<<NBLK, 256, 0, stream>>>(out2, batch, diag, pool);
  k_final<<<1, 128, 0, stream>>>(pool, diag, d_out);
}

// Round 5
// 402.434 us; speedup vs baseline: 2.2565x; 1.3705x over previous
//
#include <hip/hip_runtime.h>

// GCN: 100K nodes, 3.2M edges, 128 -> 16 -> 16 -> 16 -> 2, mean-pool to 64 graphs.
// R5: h stored bf16-packed (3.2MB -> fits per-XCD L2), aggregation fused with
// next-layer transform via width-8 shuffles (t16/t3 kernels eliminated).
// CSR build via deterministic bucket sort. Dtype-adaptive IO.

#define NN 100000
#define NE 3200000
#define NF 128
#define NH 16
#define NO 2
#define NG 64
#define NBLK 391        // ceil(NN/256)
#define NBUK 782        // ceil(NN/128), bucket = dst >> 7
#define CHUNK 4096
#define NBLKA 782       // ceil(NE/CHUNK)
#define CAP 5120        // max edges/bucket in k_bsort

// ---------------- dtype-dispatched IO helpers ----------------

__device__ __forceinline__ float ldf(const void* p, int i, int f32) {
  if (f32) return ((const float*)p)[i];
  unsigned int u = ((const unsigned short*)p)[i];
  return __uint_as_float(u << 16);
}
__device__ __forceinline__ int ldi(const void* p, int i, int i64) {
  if (i64) return (int)((const long long*)p)[i];
  return ((const int*)p)[i];
}
__device__ __forceinline__ void stf(void* p, int i, float v, int f32) {
  if (f32) {
    ((float*)p)[i] = v;
  } else {
    unsigned int w = __float_as_uint(v);
    unsigned int r = (w + 0x7fffu + ((w >> 16) & 1u)) >> 16;
    ((unsigned short*)p)[i] = (unsigned short)r;
  }
}
__device__ __forceinline__ float bf16lo(unsigned int u) { return __uint_as_float(u << 16); }
__device__ __forceinline__ float bf16hi(unsigned int u) { return __uint_as_float(u & 0xffff0000u); }
__device__ __forceinline__ unsigned int packbf(float x, float y) {
  unsigned int a = __float_as_uint(x);
  a = (a + 0x7fffu + ((a >> 16) & 1u)) >> 16;
  unsigned int b = __float_as_uint(y);
  b = (b + 0x7fffu + ((b >> 16) & 1u)) & 0xffff0000u;
  return a | b;
}
__device__ __forceinline__ int okf(float v) { return (v == v) && (fabsf(v) < 1e30f); }
__device__ __forceinline__ void nflag(int* diag, int bad, int bit) {
  if (__any(bad)) {
    if ((threadIdx.x & 63) == 0) atomicOr(diag + 2, 1 << bit);
  }
}
__device__ __forceinline__ int clampi(int v, int hi) {
  return (unsigned)v < (unsigned)hi ? v : 0;
}

// ---------------- dtype sniff (one wave, parallel) ----------------

// diag[0]=floats-are-fp32, diag[1]=ints-are-int64, diag[2]=error bitmap
__global__ __launch_bounds__(64) void k_sniff(const void* x, const void* ei, int* diag) {
  int lane = threadIdx.x;
  unsigned int xv = ((const unsigned int*)x)[lane];
  unsigned int e = (xv >> 7) & 0xffu;  // exponent of LOW half-word decoded as bf16
  int hit = (e >= 116u && e <= 133u);
  int hits = __popcll(__ballot(hit));
  unsigned int ev = ((const unsigned int*)ei)[2 * lane + 1];
  int nzc = __popcll(__ballot(ev != 0u));
  if (lane == 0) {
    diag[0] = (hits < 32) ? 1 : 0;  // bf16 x -> nearly all low half-words look like N(0,1)
    diag[1] = (nzc == 0) ? 1 : 0;   // int64 high words all zero
  }
}

// ---------------- CSR build: two-level bucket sort ----------------

__global__ __launch_bounds__(256) void k_count(const void* ei, const int* __restrict__ diag,
                                               int* __restrict__ matrix) {
  __shared__ int lh[NBUK];
  int tid = threadIdx.x, blk = blockIdx.x;
  for (int b = tid; b < NBUK; b += 256) lh[b] = 0;
  __syncthreads();
  int i64 = diag[1];
  int base = blk * CHUNK;
  int n = NE - base; n = n > CHUNK ? CHUNK : n;
  for (int i = tid; i < n; i += 256) {
    int d = clampi(ldi(ei, NE + base + i, i64), NN);
    atomicAdd(&lh[d >> 7], 1);
  }
  __syncthreads();
  for (int b = tid; b < NBUK; b += 256) matrix[blk * NBUK + b] = lh[b];
}

__global__ __launch_bounds__(256) void k_rowscan(int* __restrict__ matrix, int* __restrict__ bucket_start) {
  __shared__ int s[1024];
  int tid = threadIdx.x, b = blockIdx.x;
#pragma unroll
  for (int k = 0; k < 4; ++k) {
    int i = tid + 256 * k;
    s[i] = (i < NBLKA) ? matrix[i * NBUK + b] : 0;
  }
  __syncthreads();
  for (int off = 1; off < 1024; off <<= 1) {
    int v[4];
#pragma unroll
    for (int k = 0; k < 4; ++k) { int i = tid + 256 * k; v[k] = (i >= off) ? s[i - off] : 0; }
    __syncthreads();
#pragma unroll
    for (int k = 0; k < 4; ++k) s[tid + 256 * k] += v[k];
    __syncthreads();
  }
#pragma unroll
  for (int k = 0; k < 4; ++k) {
    int i = tid + 256 * k;
    if (i < NBLKA) matrix[i * NBUK + b] = (i > 0) ? s[i - 1] : 0;
  }
  if (tid == 0) bucket_start[b] = s[1023];
}

__global__ __launch_bounds__(1024) void k_sscan(int* __restrict__ bucket_start, int* __restrict__ rowstart) {
  __shared__ int s[1024];
  int tid = threadIdx.x;
  s[tid] = (tid < NBUK) ? bucket_start[tid] : 0;
  __syncthreads();
  for (int off = 1; off < 1024; off <<= 1) {
    int v = (tid >= off) ? s[tid - off] : 0;
    __syncthreads();
    s[tid] += v;
    __syncthreads();
  }
  if (tid < NBUK) bucket_start[tid] = (tid > 0) ? s[tid - 1] : 0;
  if (tid == 0) { bucket_start[NBUK] = s[1023]; rowstart[NN] = NE; }
}

__global__ __launch_bounds__(256) void k_bscatter(const void* ei, const int* __restrict__ diag,
                                                  const int* __restrict__ matrix,
                                                  const int* __restrict__ bucket_start,
                                                  int* __restrict__ ents) {
  __shared__ int ssrc[CHUNK];
  __shared__ int sdst[CHUNK];
  __shared__ int spkt[CHUNK];
  __shared__ int gpos[CHUNK];
  __shared__ int lhist[1024];
  __shared__ int lcur[NBUK];
  __shared__ int goff[NBUK];
  int tid = threadIdx.x, blk = blockIdx.x;
#pragma unroll
  for (int k = 0; k < 4; ++k) lhist[tid + 256 * k] = 0;
  __syncthreads();
  int i64 = diag[1];
  int base = blk * CHUNK;
  int n = NE - base; n = n > CHUNK ? CHUNK : n;
  for (int i = tid; i < n; i += 256) {
    int sv = clampi(ldi(ei, base + i, i64), NN);
    int dv = clampi(ldi(ei, NE + base + i, i64), NN);
    ssrc[i] = sv; sdst[i] = dv;
    atomicAdd(&lhist[dv >> 7], 1);
  }
  __syncthreads();
  for (int off = 1; off < 1024; off <<= 1) {
    int v[4];
#pragma unroll
    for (int k = 0; k < 4; ++k) { int i = tid + 256 * k; v[k] = (i >= off) ? lhist[i - off] : 0; }
    __syncthreads();
#pragma unroll
    for (int k = 0; k < 4; ++k) lhist[tid + 256 * k] += v[k];
    __syncthreads();
  }
  for (int b = tid; b < NBUK; b += 256) {
    int excl = (b > 0) ? lhist[b - 1] : 0;
    lcur[b] = excl;
    goff[b] = bucket_start[b] + matrix[blk * NBUK + b] - excl;
  }
  __syncthreads();
  for (int i = tid; i < n; i += 256) {
    int dv = sdst[i], b = dv >> 7;
    int r = atomicAdd(&lcur[b], 1);
    spkt[r] = ((dv & 127) << 17) | ssrc[i];
    gpos[r] = goff[b] + r;
  }
  __syncthreads();
  for (int i = tid; i < n; i += 256) ents[gpos[i]] = spkt[i];
}

__global__ __launch_bounds__(256) void k_bsort(int* __restrict__ ents, const int* __restrict__ bucket_start,
                                               int* __restrict__ rowstart, float* __restrict__ dinv,
                                               int* __restrict__ diag) {
  __shared__ int ent[CAP];
  __shared__ int sorted[CAP];
  __shared__ int lh[128];
  __shared__ int lcur[128];
  int tid = threadIdx.x, b = blockIdx.x;
  int bs = bucket_start[b], be = bucket_start[b + 1];
  int n = be - bs;
  if (n > CAP) { n = CAP; if (tid == 0) atomicOr(diag + 2, 1 << 9); }
  for (int i = tid; i < n; i += 256) ent[i] = ents[bs + i];
  if (tid < 128) lh[tid] = 0;
  __syncthreads();
  for (int i = tid; i < n; i += 256) atomicAdd(&lh[ent[i] >> 17], 1);
  __syncthreads();
  int node0 = b << 7;
  int nn = NN - node0; nn = nn > 128 ? 128 : nn;
  int myc = (tid < 128) ? lh[tid] : 0;
  for (int off = 1; off < 128; off <<= 1) {
    int v = 0;
    if (tid < 128 && tid >= off) v = lh[tid - off];
    __syncthreads();
    if (tid < 128) lh[tid] += v;
    __syncthreads();
  }
  if (tid < 128) {
    int excl = (tid > 0) ? lh[tid - 1] : 0;
    lcur[tid] = excl;
    if (tid < nn) {
      rowstart[node0 + tid] = bs + excl;
      dinv[node0 + tid] = rsqrtf((float)(myc + 1));
    }
  }
  __syncthreads();
  for (int i = tid; i < n; i += 256) {
    int e = ent[i];
    int r = atomicAdd(&lcur[e >> 17], 1);
    sorted[r] = e & 0x1FFFF;
  }
  __syncthreads();
  for (int i = tid; i < n; i += 256) ents[bs + i] = sorted[i];
}

// ---------------- input transform: hs0 = dinv * (x @ W0), bf16-packed ----------------

__global__ __launch_bounds__(256) void k_t0(const void* __restrict__ x, const void* __restrict__ W0,
                                            const float* __restrict__ dinv,
                                            int* __restrict__ diag, unsigned int* __restrict__ out) {
  __shared__ float ws[NF * NH];
  __shared__ float xs[16 * 129];
  int tid = threadIdx.x;
  int f32 = diag[0];
  int node0 = blockIdx.x * 16;
#pragma unroll
  for (int r = 0; r < 8; ++r) ws[tid + 256 * r] = ldf(W0, tid + 256 * r, f32);
#pragma unroll
  for (int r = 0; r < 8; ++r) {
    int idx = tid + 256 * r;
    int row = idx >> 7, col = idx & 127;
    xs[row * 129 + col] = ldf(x, (node0 + row) * NF + col, f32);
  }
  __syncthreads();
  int nl = tid >> 4, f = tid & 15;
  float acc = 0.f;
#pragma unroll 4
  for (int k = 0; k < NF; ++k) acc += xs[nl * 129 + k] * ws[k * NH + f];
  acc *= dinv[node0 + nl];
  float other = __shfl_xor(acc, 1);  // partner feature (adjacent lane)
  if ((f & 1) == 0) out[(node0 + nl) * 8 + (f >> 1)] = packbf(acc, other);
  nflag(diag, !okf(acc), 0);
}

// ---------------- fused aggregate + PReLU + next transform ----------------

// in : hs (bf16x2 packed, prescaled by dinv)
// out: hs_next[i][:] = dinv[i] * ( prelu(dinv[i]*(sum_nb hs + hs[i]) + b) @ Wn )
// 8 threads/node, thread p owns features 2p, 2p+1.
__global__ __launch_bounds__(256) void k_aggT(const unsigned int* __restrict__ hin,
                                              const int* __restrict__ srcs,
                                              const int* __restrict__ rowstart,
                                              const float* __restrict__ dinv,
                                              const void* __restrict__ b, const void* __restrict__ a,
                                              const void* __restrict__ Wn,
                                              int* __restrict__ diag, int bit,
                                              unsigned int* __restrict__ hout) {
  __shared__ float ws[NH * NH];
  int tid = threadIdx.x;
  int f32 = diag[0];
  ws[tid] = ldf(Wn, tid, f32);
  __syncthreads();
  int gid = blockIdx.x * 256 + tid;  // NN*8 = 800000, /256 = 3125 exact
  int node = gid >> 3, p = gid & 7;
  unsigned int self = hin[node * 8 + p];
  float acc0 = bf16lo(self), acc1 = bf16hi(self);
  int e0 = rowstart[node], e1 = rowstart[node + 1];
  for (int e = e0; e < e1; ++e) {
    int s = srcs[e];
    s = (unsigned)s < NN ? s : 0;
    unsigned int v = hin[s * 8 + p];
    acc0 += bf16lo(v);
    acc1 += bf16hi(v);
  }
  float dv = dinv[node];
  float av = ldf(a, 0, f32);
  float p0 = dv * acc0 + ldf(b, 2 * p, f32);
  float p1 = dv * acc1 + ldf(b, 2 * p + 1, f32);
  p0 = p0 > 0.f ? p0 : av * p0;
  p1 = p1 > 0.f ? p1 : av * p1;
  // t[f'] = sum_k p[k] * Wn[k][f'] for f' = 2p, 2p+1 (gather p[k] via width-8 shuffles)
  float t0 = 0.f, t1 = 0.f;
#pragma unroll
  for (int j = 0; j < 8; ++j) {
    float qa = __shfl(p0, j, 8);
    float qb = __shfl(p1, j, 8);
    t0 += qa * ws[(2 * j) * NH + 2 * p]     + qb * ws[(2 * j + 1) * NH + 2 * p];
    t1 += qa * ws[(2 * j) * NH + 2 * p + 1] + qb * ws[(2 * j + 1) * NH + 2 * p + 1];
  }
  t0 *= dv;
  t1 *= dv;
  hout[node * 8 + p] = packbf(t0, t1);
  nflag(diag, !okf(t0) || !okf(t1), bit);
}

// Last hidden layer: aggregate + PReLU + W3 (16->2), output float2 prescaled by dinv.
__global__ __launch_bounds__(256) void k_aggT3(const unsigned int* __restrict__ hin,
                                               const int* __restrict__ srcs,
                                               const int* __restrict__ rowstart,
                                               const float* __restrict__ dinv,
                                               const void* __restrict__ b, const void* __restrict__ a,
                                               const void* __restrict__ W3,
                                               int* __restrict__ diag, float2* __restrict__ hout) {
  __shared__ float ws[NH * NO];
  int tid = threadIdx.x;
  int f32 = diag[0];
  if (tid < NH * NO) ws[tid] = ldf(W3, tid, f32);
  __syncthreads();
  int gid = blockIdx.x * 256 + tid;
  int node = gid >> 3, p = gid & 7;
  unsigned int self = hin[node * 8 + p];
  float acc0 = bf16lo(self), acc1 = bf16hi(self);
  int e0 = rowstart[node], e1 = rowstart[node + 1];
  for (int e = e0; e < e1; ++e) {
    int s = srcs[e];
    s = (unsigned)s < NN ? s : 0;
    unsigned int v = hin[s * 8 + p];
    acc0 += bf16lo(v);
    acc1 += bf16hi(v);
  }
  float dv = dinv[node];
  float av = ldf(a, 0, f32);
  float p0 = dv * acc0 + ldf(b, 2 * p, f32);
  float p1 = dv * acc1 + ldf(b, 2 * p + 1, f32);
  p0 = p0 > 0.f ? p0 : av * p0;
  p1 = p1 > 0.f ? p1 : av * p1;
  float u0 = p0 * ws[(2 * p) * NO] + p1 * ws[(2 * p + 1) * NO];
  float u1 = p0 * ws[(2 * p) * NO + 1] + p1 * ws[(2 * p + 1) * NO + 1];
#pragma unroll
  for (int off = 1; off < 8; off <<= 1) {
    u0 += __shfl_xor(u0, off, 8);
    u1 += __shfl_xor(u1, off, 8);
  }
  if (p == 0) hout[node] = make_float2(dv * u0, dv * u1);
  nflag(diag, !okf(u0) || !okf(u1), 6);
}

// Final aggregation (2-wide), adds b3.
__global__ __launch_bounds__(256) void k_agg2(const float2* __restrict__ tin,
                                              const int* __restrict__ srcs,
                                              const int* __restrict__ rowstart,
                                              const float* __restrict__ dinv,
                                              const void* __restrict__ b3,
                                              int* __restrict__ diag, float2* __restrict__ out) {
  int node = blockIdx.x * 256 + threadIdx.x;
  if (node >= NN) return;
  int f32 = diag[0];
  float2 t = tin[node];
  float a0 = t.x, a1 = t.y;
  int e0 = rowstart[node], e1 = rowstart[node + 1];
  for (int e = e0; e < e1; ++e) {
    int s = srcs[e];
    s = (unsigned)s < NN ? s : 0;
    float2 hv = tin[s];
    a0 += hv.x;
    a1 += hv.y;
  }
  float dv = dinv[node];
  a0 = dv * a0 + ldf(b3, 0, f32);
  a1 = dv * a1 + ldf(b3, 1, f32);
  out[node] = make_float2(a0, a1);
  nflag(diag, !okf(a0) || !okf(a1), 7);
}

// ---------------- pooling ----------------

__global__ __launch_bounds__(256) void k_pool(const float2* __restrict__ h, const void* __restrict__ batch,
                                              const int* __restrict__ diag, float* __restrict__ pool) {
  __shared__ float ssum[NG * NO];
  __shared__ float scnt[NG];
  int tid = threadIdx.x;
  if (tid < NG * NO) ssum[tid] = 0.f;
  if (tid < NG) scnt[tid] = 0.f;
  __syncthreads();
  int i = blockIdx.x * 256 + tid;
  if (i < NN) {
    int i64 = diag[1];
    int g = ldi(batch, i, i64);
    g = (unsigned)g < NG ? g : 0;
    float2 v = h[i];
    atomicAdd(&ssum[g * 2], v.x);
    atomicAdd(&ssum[g * 2 + 1], v.y);
    atomicAdd(&scnt[g], 1.f);
  }
  __syncthreads();
  if (tid < NG * NO && ssum[tid] != 0.f) atomicAdd(&pool[tid], ssum[tid]);
  if (tid < NG && scnt[tid] != 0.f) atomicAdd(&pool[NG * NO + tid], scnt[tid]);
}

__global__ __launch_bounds__(128) void k_final(const float* __restrict__ pool,
                                               const int* __restrict__ diag, void* __restrict__ out) {
  int i = threadIdx.x;
  int f32 = diag[0], i64 = diag[1], stg = diag[2];
  float c = pool[NG * NO + (i >> 1)];
  c = c > 1.f ? c : 1.f;
  float v = pool[i] / c;
  if (stg != 0 || !okf(v)) {
    int stage = stg ? __ffs(stg) : 15;
    v = 1024.0f + stage * 64.0f + f32 * 16.0f + i64 * 8.0f;
  }
  stf(out, i, v, f32);
}

__global__ __launch_bounds__(128) void k_diag_ws(void* out, float v) {
  unsigned int w = __float_as_uint(v);
  ((unsigned short*)out)[threadIdx.x] = (unsigned short)(w >> 16);
}

// ---------------- launch ----------------

extern "C" void kernel_launch(void* const* d_in, const int* in_sizes, int n_in,
                              void* d_out, int out_size, void* d_ws, size_t ws_size,
                              hipStream_t stream) {
  const void* x  = d_in[0];
  const void* ei = d_in[1];
  const void* batch = d_in[2];
  const void* W0 = d_in[3];
  const void* b0 = d_in[4];
  const void* a0 = d_in[5];
  const void* W1 = d_in[6];
  const void* b1 = d_in[7];
  const void* a1 = d_in[8];
  const void* W2 = d_in[9];
  const void* b2 = d_in[10];
  const void* a2 = d_in[11];
  const void* W3 = d_in[12];
  const void* b3 = d_in[13];

  // workspace layout (bytes)
  char* w = (char*)d_ws;
  int* diag         = (int*)(w + 0);           // 64
  float* pool       = (float*)(w + 64);        // 768 -> pad 896
  float* dinv       = (float*)(w + 896);       // 400000 -> pad 400960
  int* rowstart     = (int*)(w + 400960);      // 400004 -> pad 801088
  int* bucket_start = (int*)(w + 801088);      // 3132 -> pad 804288
  int* ents         = (int*)(w + 804288);      // 12.8MB -> 13604288 (becomes CSR srcs)
  unsigned int* hsA = (unsigned int*)(w + 13604288);  // 3.2MB -> 16804288 (bf16x2 packed)
  unsigned int* hsB = (unsigned int*)(w + 16804288);  // 3.2MB -> 20004288
  float2* hs3       = (float2*)(w + 20004288); // 800000 -> 20804288
  float2* out2      = (float2*)(w + 20804288); // 800000 -> 21604288
  int* matrix       = (int*)hsA;               // 2446096 B overlay, dead before k_t0
  const size_t NEED = 21604288;

  if (ws_size < NEED) {
    k_diag_ws<<<1, 128, 0, stream>>>(d_out, (float)ws_size);
    return;
  }

  hipMemsetAsync(d_ws, 0, 832, stream);  // diag + pool

  k_sniff<<<1, 64, 0, stream>>>(x, ei, diag);

  // CSR build (deterministic bucket sort)
  k_count<<<NBLKA, 256, 0, stream>>>(ei, diag, matrix);
  k_rowscan<<<NBUK, 256, 0, stream>>>(matrix, bucket_start);
  k_sscan<<<1, 1024, 0, stream>>>(bucket_start, rowstart);
  k_bscatter<<<NBLKA, 256, 0, stream>>>(ei, diag, matrix, bucket_start, ents);
  k_bsort<<<NBUK, 256, 0, stream>>>(ents, bucket_start, rowstart, dinv, diag);

  // layers (transform fused into aggregation epilogue; h stored bf16-packed)
  k_t0<<<NN / 16, 256, 0, stream>>>(x, W0, dinv, diag, hsA);
  k_aggT<<<NN * 8 / 256, 256, 0, stream>>>(hsA, ents, rowstart, dinv, b0, a0, W1, diag, 1, hsB);
  k_aggT<<<NN * 8 / 256, 256, 0, stream>>>(hsB, ents, rowstart, dinv, b1, a1, W2, diag, 3, hsA);
  k_aggT3<<<NN * 8 / 256, 256, 0, stream>>>(hsA, ents, rowstart, dinv, b2, a2, W3, diag, hs3);
  k_agg2<<<NBLK, 256, 0, stream>>>(hs3, ents, rowstart, dinv, b3, diag, out2);

  k_pool<<<NBLK, 256, 0, stream>>>(out2, batch, diag, pool);
  k_final<<<1, 128, 0, stream>>>(pool, diag, d_out);
}